// Round 1
// baseline (2189.868 us; speedup 1.0000x reference)
//
#include <hip/hip_runtime.h>

// LightGCN propagation: acc = (h0 + h1 + h2 + h3)/4, h_{l+1} = G @ h_l
// G given as COO (vals, src, dst), D^-1/2 A D^-1/2 normalized social graph.
// D = 64 (one wave covers one edge's full feature row).

#define DIM 64

__global__ void copy_kernel(const float4* __restrict__ in, float4* __restrict__ out, int n4) {
    int i = blockIdx.x * blockDim.x + threadIdx.x;
    int stride = gridDim.x * blockDim.x;
    for (; i < n4; i += stride) out[i] = in[i];
}

__global__ void add_kernel(float4* __restrict__ acc, const float4* __restrict__ h, int n4) {
    int i = blockIdx.x * blockDim.x + threadIdx.x;
    int stride = gridDim.x * blockDim.x;
    for (; i < n4; i += stride) {
        float4 a = acc[i], b = h[i];
        a.x += b.x; a.y += b.y; a.z += b.z; a.w += b.w;
        acc[i] = a;
    }
}

__global__ void add_scale_kernel(float4* __restrict__ acc, const float4* __restrict__ h,
                                 int n4, float scale) {
    int i = blockIdx.x * blockDim.x + threadIdx.x;
    int stride = gridDim.x * blockDim.x;
    for (; i < n4; i += stride) {
        float4 a = acc[i], b = h[i];
        a.x = (a.x + b.x) * scale;
        a.y = (a.y + b.y) * scale;
        a.z = (a.z + b.z) * scale;
        a.w = (a.w + b.w) * scale;
        acc[i] = a;
    }
}

// One wave per edge; lane = feature dim. Gather coalesced 256B, scatter via
// coalesced atomics (64 consecutive dwords -> 4 cache lines per edge).
__global__ void spmm_atomic(const float* __restrict__ vals, const int* __restrict__ src,
                            const int* __restrict__ dst, const float* __restrict__ x,
                            float* __restrict__ y, int n_edges) {
    int lane = threadIdx.x & 63;
    int wave = (blockIdx.x * blockDim.x + threadIdx.x) >> 6;
    int nwaves = (gridDim.x * blockDim.x) >> 6;
    for (int e = wave; e < n_edges; e += nwaves) {
        float v = vals[e];          // wave-uniform
        int s = src[e];             // wave-uniform
        int d = dst[e];             // wave-uniform
        float m = v * x[(size_t)s * DIM + lane];
        atomicAdd(&y[(size_t)d * DIM + lane], m);
    }
}

extern "C" void kernel_launch(void* const* d_in, const int* in_sizes, int n_in,
                              void* d_out, int out_size, void* d_ws, size_t ws_size,
                              hipStream_t stream) {
    const float* user_emb  = (const float*)d_in[0];
    const float* edge_vals = (const float*)d_in[1];
    const int*   edge_src  = (const int*)d_in[2];
    const int*   edge_dst  = (const int*)d_in[3];
    float* out = (float*)d_out;

    const int n_users = in_sizes[0] / DIM;
    const int n_edges = in_sizes[1];
    const size_t nfloats = (size_t)n_users * DIM;
    const int n4 = (int)(nfloats / 4);

    float* h_a = (float*)d_ws;
    float* h_b = h_a + nfloats;

    dim3 blk(256);
    dim3 grid_ew(2048);
    dim3 grid_spmm(4096);   // 16384 waves, ~195 edges/wave grid-stride

    // acc = h0
    copy_kernel<<<grid_ew, blk, 0, stream>>>((const float4*)user_emb, (float4*)out, n4);

    // layer 1: h_a = G @ h0 ; acc += h_a
    hipMemsetAsync(h_a, 0, nfloats * sizeof(float), stream);
    spmm_atomic<<<grid_spmm, blk, 0, stream>>>(edge_vals, edge_src, edge_dst,
                                               user_emb, h_a, n_edges);
    add_kernel<<<grid_ew, blk, 0, stream>>>((float4*)out, (const float4*)h_a, n4);

    // layer 2: h_b = G @ h_a ; acc += h_b
    hipMemsetAsync(h_b, 0, nfloats * sizeof(float), stream);
    spmm_atomic<<<grid_spmm, blk, 0, stream>>>(edge_vals, edge_src, edge_dst,
                                               h_a, h_b, n_edges);
    add_kernel<<<grid_ew, blk, 0, stream>>>((float4*)out, (const float4*)h_b, n4);

    // layer 3: h_a = G @ h_b ; acc = (acc + h_a) / 4
    hipMemsetAsync(h_a, 0, nfloats * sizeof(float), stream);
    spmm_atomic<<<grid_spmm, blk, 0, stream>>>(edge_vals, edge_src, edge_dst,
                                               h_b, h_a, n_edges);
    add_scale_kernel<<<grid_ew, blk, 0, stream>>>((float4*)out, (const float4*)h_a,
                                                  n4, 0.25f);
}

// Round 2
// 810.752 us; speedup vs baseline: 2.7010x; 2.7010x over previous
//
#include <hip/hip_runtime.h>

// LightGCN propagation: out = (h0 + h1 + h2 + h3)/4, h_{l+1} = G @ h_l
// G = COO (vals, src, dst). Strategy: build CSR by dst on-device once per
// call (atomics were the round-1 bottleneck: 819 MB write-through per spmm),
// then 3x atomic-free spmm: one wave per dst row, 4 edges in flight per wave
// (4 groups x 16 lanes x float4), shfl_xor reduce, single 256B store.

#define DIM 64
#define SCAN_BLK 256
#define SCAN_EPT 8
#define SCAN_TILE (SCAN_BLK * SCAN_EPT)

__global__ void hist_kernel(const int* __restrict__ dst, int* __restrict__ cnt, int n_edges) {
    int i = blockIdx.x * blockDim.x + threadIdx.x;
    int stride = gridDim.x * blockDim.x;
    for (; i < n_edges; i += stride) atomicAdd(&cnt[dst[i]], 1);
}

// In-place exclusive scan of tiles; per-block totals to partials.
__global__ void scan_block_kernel(int* __restrict__ data, int* __restrict__ partials, int n) {
    __shared__ int sh[SCAN_BLK];
    int base = blockIdx.x * SCAN_TILE + threadIdx.x * SCAN_EPT;
    int v[SCAN_EPT];
    int sum = 0;
#pragma unroll
    for (int j = 0; j < SCAN_EPT; j++) {
        int idx = base + j;
        int c = (idx < n) ? data[idx] : 0;
        v[j] = sum;      // prefix within thread (exclusive)
        sum += c;
    }
    sh[threadIdx.x] = sum;
    __syncthreads();
    for (int off = 1; off < SCAN_BLK; off <<= 1) {
        int t = (threadIdx.x >= off) ? sh[threadIdx.x - off] : 0;
        __syncthreads();
        sh[threadIdx.x] += t;
        __syncthreads();
    }
    int excl = (threadIdx.x == 0) ? 0 : sh[threadIdx.x - 1];
#pragma unroll
    for (int j = 0; j < SCAN_EPT; j++) {
        int idx = base + j;
        if (idx < n) data[idx] = excl + v[j];
    }
    if (threadIdx.x == SCAN_BLK - 1) partials[blockIdx.x] = sh[SCAN_BLK - 1];
}

// Single block: exclusive scan of block partials (nb <= 256).
__global__ void scan_partials_kernel(int* __restrict__ partials, int nb) {
    __shared__ int sh[SCAN_BLK];
    int v = (threadIdx.x < nb) ? partials[threadIdx.x] : 0;
    sh[threadIdx.x] = v;
    __syncthreads();
    for (int off = 1; off < SCAN_BLK; off <<= 1) {
        int t = (threadIdx.x >= off) ? sh[threadIdx.x - off] : 0;
        __syncthreads();
        sh[threadIdx.x] += t;
        __syncthreads();
    }
    int excl = (threadIdx.x == 0) ? 0 : sh[threadIdx.x - 1];
    if (threadIdx.x < nb) partials[threadIdx.x] = excl;
}

__global__ void add_offsets_kernel(int* __restrict__ data, const int* __restrict__ partials, int n) {
    int i = blockIdx.x * blockDim.x + threadIdx.x;
    if (i < n) data[i] += partials[i / SCAN_TILE];
}

// row_off holds row starts; after this it holds row ENDS (start of r = end of r-1).
__global__ void scatter_kernel(const float* __restrict__ vals, const int* __restrict__ src,
                               const int* __restrict__ dst, int* __restrict__ row_off,
                               int2* __restrict__ edges, int n_edges) {
    int i = blockIdx.x * blockDim.x + threadIdx.x;
    int stride = gridDim.x * blockDim.x;
    for (; i < n_edges; i += stride) {
        int d = dst[i];
        int p = atomicAdd(&row_off[d], 1);
        edges[p] = make_int2(src[i], __float_as_int(vals[i]));
    }
}

// One wave per dst row. 4 lane-groups of 16; group g walks edges start+g, +4...
// Each lane accumulates a float4 (dims sl*4..sl*4+3); xor-reduce across groups.
// MODE 0: h_out = h; acc = x[row] + h      (layer 1, x = user_emb)
// MODE 1: h_out = h; acc += h              (layer 2)
// MODE 2: acc = (acc + h) * 0.25           (layer 3, no h store)
template <int MODE>
__global__ void spmm_csr(const int2* __restrict__ edges, const int* __restrict__ row_end,
                         const float* __restrict__ x, float* __restrict__ h_out,
                         float* __restrict__ acc, int n_rows) {
    int row = blockIdx.x * (blockDim.x >> 6) + (threadIdx.x >> 6);
    if (row >= n_rows) return;
    int lane = threadIdx.x & 63;
    int g = lane >> 4;       // edge group 0..3
    int sl = lane & 15;      // covers dims sl*4 .. sl*4+3

    int start = (row == 0) ? 0 : row_end[row - 1];
    int end = row_end[row];

    float4 a = make_float4(0.f, 0.f, 0.f, 0.f);
    for (int e = start + g; e < end; e += 4) {
        int2 ev = edges[e];
        float v = __int_as_float(ev.y);
        const float4 xv = *(const float4*)&x[(size_t)ev.x * DIM + sl * 4];
        a.x += v * xv.x; a.y += v * xv.y; a.z += v * xv.z; a.w += v * xv.w;
    }
    // reduce the 4 groups (lanes xor 16, xor 32 hold the same dims)
    a.x += __shfl_xor(a.x, 16, 64); a.y += __shfl_xor(a.y, 16, 64);
    a.z += __shfl_xor(a.z, 16, 64); a.w += __shfl_xor(a.w, 16, 64);
    a.x += __shfl_xor(a.x, 32, 64); a.y += __shfl_xor(a.y, 32, 64);
    a.z += __shfl_xor(a.z, 32, 64); a.w += __shfl_xor(a.w, 32, 64);

    size_t base = (size_t)row * DIM + sl * 4;
    if (MODE == 0) {
        if (g == 0) *(float4*)&h_out[base] = a;
        if (g == 1) {
            float4 x0 = *(const float4*)&x[base];
            x0.x += a.x; x0.y += a.y; x0.z += a.z; x0.w += a.w;
            *(float4*)&acc[base] = x0;
        }
    } else if (MODE == 1) {
        if (g == 0) *(float4*)&h_out[base] = a;
        if (g == 1) {
            float4 c = *(const float4*)&acc[base];
            c.x += a.x; c.y += a.y; c.z += a.z; c.w += a.w;
            *(float4*)&acc[base] = c;
        }
    } else {
        if (g == 0) {
            float4 c = *(const float4*)&acc[base];
            c.x = (c.x + a.x) * 0.25f; c.y = (c.y + a.y) * 0.25f;
            c.z = (c.z + a.z) * 0.25f; c.w = (c.w + a.w) * 0.25f;
            *(float4*)&acc[base] = c;
        }
    }
}

extern "C" void kernel_launch(void* const* d_in, const int* in_sizes, int n_in,
                              void* d_out, int out_size, void* d_ws, size_t ws_size,
                              hipStream_t stream) {
    const float* user_emb  = (const float*)d_in[0];
    const float* edge_vals = (const float*)d_in[1];
    const int*   edge_src  = (const int*)d_in[2];
    const int*   edge_dst  = (const int*)d_in[3];
    float* out = (float*)d_out;

    const int n_users = in_sizes[0] / DIM;
    const int n_edges = in_sizes[1];
    const size_t nfloats = (size_t)n_users * DIM;

    // workspace carve-up
    char* ws = (char*)d_ws;
    float* h_a    = (float*)ws;                      ws += nfloats * sizeof(float);
    float* h_b    = (float*)ws;                      ws += nfloats * sizeof(float);
    int2*  edges  = (int2*)ws;                       ws += (size_t)n_edges * sizeof(int2);
    int*   row    = (int*)ws;                        ws += (size_t)n_users * sizeof(int);
    int*   parts  = (int*)ws;                        ws += 256 * sizeof(int);

    const int nb_scan = (n_users + SCAN_TILE - 1) / SCAN_TILE;   // 98

    // ---- build CSR by dst (once per call, reused by all 3 layers) ----
    hipMemsetAsync(row, 0, (size_t)n_users * sizeof(int), stream);
    hist_kernel<<<1024, 256, 0, stream>>>(edge_dst, row, n_edges);
    scan_block_kernel<<<nb_scan, SCAN_BLK, 0, stream>>>(row, parts, n_users);
    scan_partials_kernel<<<1, SCAN_BLK, 0, stream>>>(parts, nb_scan);
    add_offsets_kernel<<<(n_users + 255) / 256, 256, 0, stream>>>(row, parts, n_users);
    scatter_kernel<<<1024, 256, 0, stream>>>(edge_vals, edge_src, edge_dst, row, edges, n_edges);
    // row[] now holds row ENDS.

    // ---- 3 propagation layers, atomic-free ----
    const int waves_per_blk = 4;                      // 256 threads
    const int nblk = (n_users + waves_per_blk - 1) / waves_per_blk;
    spmm_csr<0><<<nblk, 256, 0, stream>>>(edges, row, user_emb, h_a, out, n_users);
    spmm_csr<1><<<nblk, 256, 0, stream>>>(edges, row, h_a, h_b, out, n_users);
    spmm_csr<2><<<nblk, 256, 0, stream>>>(edges, row, h_b, nullptr, out, n_users);
}